// Round 2
// baseline (3290.176 us; speedup 1.0000x reference)
//
#include <hip/hip_runtime.h>

typedef unsigned short u16;
typedef __bf16 bf16x8 __attribute__((ext_vector_type(8)));
typedef float f32x4 __attribute__((ext_vector_type(4)));

union FragU { bf16x8 v; u16 u[8]; uint4 q; };

__device__ __forceinline__ float bf2f(u16 u) {
  union { unsigned int i; float f; } x; x.i = ((unsigned int)u) << 16; return x.f;
}
__device__ __forceinline__ u16 f2bf(float f) {
  union { float f; unsigned int i; } x; x.f = f;
  return (u16)((x.i + 0x7FFFu + ((x.i >> 16) & 1u)) >> 16);
}

#define ST 72        // padded row stride (bf16 elems): 144B rows, 16B aligned, 2-way banks (free)
#define FST 136      // featsT stride (128 + 8)

// One persistent workgroup per batch (64 blocks x 768 threads = 12 waves).
// Dtype-adaptive: detects f32-vs-bf16 input storage at runtime from frames' bit patterns.
__global__ __launch_bounds__(768, 1) void cfgcn(
    const void* __restrict__ frames, const void* __restrict__ adj,
    const void* __restrict__ hid0, const void* __restrict__ encW, const void* __restrict__ encb,
    const void* __restrict__ Wfh, const void* __restrict__ Wfu, const void* __restrict__ bfp,
    const void* __restrict__ Wgh, const void* __restrict__ Wgu, const void* __restrict__ bgp,
    const void* __restrict__ Wch, const void* __restrict__ Wcu, const void* __restrict__ bcp,
    const void* __restrict__ dW1, const void* __restrict__ db1,
    const void* __restrict__ dW2, const void* __restrict__ db2,
    const void* __restrict__ dW3, const void* __restrict__ db3,
    const void* __restrict__ osc, const void* __restrict__ obi,
    void* __restrict__ outv)
{
  __shared__ alignas(16) u16 lds[64000];
  u16* sh_h   = lds +     0;   // h   row-major [n][d]
  u16* sh_hT  = lds +  4608;   // h^T [d][n]
  u16* sh_At  = lds +  9216;   // At  [n][m]
  u16* sh_AtT = lds + 13824;   // At^T
  u16* sh_S2  = lds + 18432;   // At@At
  u16* sh_xt  = lds + 23040;   // encoder out [n][d]
  u16* sh_xtT = lds + 27648;
  u16* sh_Y1  = lds + 32256;   // At@x / At@h
  u16* sh_Y2  = lds + 36864;   // S2@x / S2@h
  u16* sh_G   = lds + 41472;   // gate preacts ff|gg|cc (3*4608)
  u16* sh_fT  = lds + 55296;   // featsT [n][c] (64x136) -> ends at 64000
  __shared__ float sh_biasG[192], sh_encB[64], sh_pooled[64], sh_z1[128], sh_z2[64];
  __shared__ int sh_flag;

  const int b    = blockIdx.x;
  const int tid  = threadIdx.x;
  const int w    = tid >> 6;      // wave 0..11
  const int lane = tid & 63;
  const int quad = lane >> 4;     // 0..3
  const int l15  = lane & 15;

  // ---------------- dtype detection + LDS scrub ----------------
  if (tid == 0) sh_flag = 0;
  for (int i = tid; i < 64000; i += 768) lds[i] = 0;
  __syncthreads();
  {
    int c = 0;
    const u16* fu = (const u16*)frames;
    for (int i = tid; i < 8192; i += 768) {
      u16 u = fu[i];
      c += ((u & 0x7F80u) >= 0x6000u) ? 1 : 0;   // exponent >= 0xC0: never in bf16 N(0,1)
    }
    if (c) atomicAdd(&sh_flag, c);
  }
  __syncthreads();
  const bool isf32 = (sh_flag > 16);

  auto ldbf = [&](const void* p, int i) -> u16 {
    return isf32 ? f2bf(((const float*)p)[i]) : ((const u16*)p)[i];
  };
  auto ldf = [&](const void* p, int i) -> float {
    return isf32 ? ((const float*)p)[i] : bf2f(((const u16*)p)[i]);
  };
  auto fetch8 = [&](const void* p, int id) -> FragU {
    FragU f;
    if (!isf32) {
      f.q = ((const uint4*)p)[id];
    } else {
      const float4* fp = (const float4*)p;
      float4 lo = fp[2 * id], hi = fp[2 * id + 1];
      f.u[0] = f2bf(lo.x); f.u[1] = f2bf(lo.y); f.u[2] = f2bf(lo.z); f.u[3] = f2bf(lo.w);
      f.u[4] = f2bf(hi.x); f.u[5] = f2bf(hi.y); f.u[6] = f2bf(hi.z); f.u[7] = f2bf(hi.w);
    }
    return f;
  };
  auto stout = [&](int i, float v) {
    if (isf32) ((float*)outv)[i] = v; else ((u16*)outv)[i] = f2bf(v);
  };

  // ---------------- one-time preloads ----------------
  // Wcat B-fragments in registers: wave w owns gate cols [w*16, w*16+16).
  // Rows 0..191 = {Wf/g/c}_h[k=0..2], rows 192..383 = {Wf/g/c}_u[k=0..2].
  const void* Whp[3] = {Wfh, Wgh, Wch};
  const void* Wup[3] = {Wfu, Wgu, Wcu};
  const int gate = w >> 2;                 // 0=f 1=g 2=c
  const int colg = ((w & 3) * 16) + l15;   // col within gate block
  FragU wfrag[12];
#pragma unroll
  for (int kc = 0; kc < 12; ++kc) {
#pragma unroll
    for (int j = 0; j < 8; ++j) {
      int r = kc * 32 + quad * 8 + j;
      const void* src = (r < 192) ? Whp[gate] : Wup[gate];
      int rr = (r < 192) ? r : r - 192;
      wfrag[kc].u[j] = ldbf(src, (rr >> 6) * 4096 + (rr & 63) * 64 + colg);
    }
  }
  // encoder B-fragments (enc_W[c][d]); wave's d-tile = w&3
  FragU efrag[4];
#pragma unroll
  for (int kc = 0; kc < 4; ++kc) {
#pragma unroll
    for (int j = 0; j < 8; ++j) {
      int c = kc * 32 + quad * 8 + j;
      efrag[kc].u[j] = ldbf(encW, c * 64 + ((w & 3) * 16 + l15));
    }
  }
  if (tid < 192) {
    const void* bp = (tid < 64) ? bfp : (tid < 128 ? bgp : bcp);
    sh_biasG[tid] = ldf(bp, tid & 63);
  }
  if (tid < 64) sh_encB[tid] = ldf(encb, tid);

  // stage h0 (row-major + transposed)
  {
    const void* hg = isf32 ? (const void*)((const float*)hid0 + (size_t)b * 4096)
                           : (const void*)((const u16*)hid0 + (size_t)b * 4096);
    for (int st = tid; st < 512; st += 768) {
      FragU f = fetch8(hg, st);
      int n = st >> 3, d8 = (st & 7) * 8;
      *(uint4*)(sh_h + n * ST + d8) = f.q;
#pragma unroll
      for (int j = 0; j < 8; ++j) sh_hT[(d8 + j) * ST + n] = f.u[j];
    }
  }

  auto stage = [&](int tt, int st0, int stride) {
    const void* ag = isf32 ? (const void*)((const float*)adj + (size_t)(b * 128 + tt) * 4096)
                           : (const void*)((const u16*)adj + (size_t)(b * 128 + tt) * 4096);
    const void* fg = isf32 ? (const void*)((const float*)frames + (size_t)(b * 128 + tt) * 8192)
                           : (const void*)((const u16*)frames + (size_t)(b * 128 + tt) * 8192);
    for (int id = st0; id < 1536; id += stride) {
      if (id < 512) {                       // adjacency -> At + At^T
        FragU f = fetch8(ag, id);
        int r = id >> 3, c8 = (id & 7) * 8;
        *(uint4*)(sh_At + r * ST + c8) = f.q;
#pragma unroll
        for (int j = 0; j < 8; ++j) sh_AtT[(c8 + j) * ST + r] = f.u[j];
      } else {                              // frames [c][n] -> featsT [n][c]
        int k = id - 512;
        FragU f = fetch8(fg, k);
        int c = k >> 3, n8 = (k & 7) * 8;
#pragma unroll
        for (int j = 0; j < 8; ++j) sh_fT[(n8 + j) * FST + c] = f.u[j];
      }
    }
  };
  stage(0, tid, 768);

  // 64x64 @ 64x64 tile job: C[mt,nt] 16x16, K=64, A row-major, BT = B^T row-major
  auto tile64 = [&](const u16* A, const u16* BT, u16* C, int mt, int nt) {
    f32x4 acc = {0.f, 0.f, 0.f, 0.f};
    bf16x8 a0 = *(const bf16x8*)(A  + (mt * 16 + l15) * ST + quad * 8);
    bf16x8 b0 = *(const bf16x8*)(BT + (nt * 16 + l15) * ST + quad * 8);
    acc = __builtin_amdgcn_mfma_f32_16x16x32_bf16(a0, b0, acc, 0, 0, 0);
    bf16x8 a1 = *(const bf16x8*)(A  + (mt * 16 + l15) * ST + 32 + quad * 8);
    bf16x8 b1 = *(const bf16x8*)(BT + (nt * 16 + l15) * ST + 32 + quad * 8);
    acc = __builtin_amdgcn_mfma_f32_16x16x32_bf16(a1, b1, acc, 0, 0, 0);
    int cb = (mt * 16 + quad * 4) * ST + nt * 16 + l15;
    C[cb]          = f2bf(acc[0]);
    C[cb + ST]     = f2bf(acc[1]);
    C[cb + 2 * ST] = f2bf(acc[2]);
    C[cb + 3 * ST] = f2bf(acc[3]);
  };

  auto encTile = [&](int mt, int dt) {   // dt must be w&3 (matches efrag)
    f32x4 acc = {0.f, 0.f, 0.f, 0.f};
#pragma unroll
    for (int kc = 0; kc < 4; ++kc) {
      bf16x8 a = *(const bf16x8*)(sh_fT + (mt * 16 + l15) * FST + kc * 32 + quad * 8);
      acc = __builtin_amdgcn_mfma_f32_16x16x32_bf16(a, efrag[kc].v, acc, 0, 0, 0);
    }
    int d = dt * 16 + l15;
    float eb = sh_encB[d];
#pragma unroll
    for (int r = 0; r < 4; ++r) {
      int n = mt * 16 + quad * 4 + r;
      u16 hv = f2bf(acc[r] + eb);
      sh_xt[n * ST + d]  = hv;
      sh_xtT[d * ST + n] = hv;
    }
  };

  f32x4 gacc[4];
  auto gstep = [&](const u16* buf, int koff, const FragU& wf) {
#pragma unroll
    for (int mt = 0; mt < 4; ++mt) {
      bf16x8 a = *(const bf16x8*)(buf + (mt * 16 + l15) * ST + koff + quad * 8);
      gacc[mt] = __builtin_amdgcn_mfma_f32_16x16x32_bf16(a, wf.v, gacc[mt], 0, 0, 0);
    }
  };

  __syncthreads();

  for (int t = 0; t < 128; ++t) {
    // ---- Phase B: encoder (xt = feats@encW + b) and S2 = At@At
    encTile(w >> 2, w & 3);
    if (w < 4) encTile(3, w);
    tile64(sh_At, sh_AtT, sh_S2, w >> 2, w & 3);
    if (w < 4) tile64(sh_At, sh_AtT, sh_S2, 3, w);
    __syncthreads();

    // ---- Phase C: yx1 = At@xt, yx2 = S2@xt
#pragma unroll
    for (int i = 0; i < 3; ++i) {
      int id = w + 12 * i;
      if (id < 16)      tile64(sh_At, sh_xtT, sh_Y1, id >> 2, id & 3);
      else if (id < 32) tile64(sh_S2, sh_xtT, sh_Y2, (id - 16) >> 2, (id - 16) & 3);
    }
    __syncthreads();

    // ---- Phase D: gate += [xt, yx1, yx2] @ W_u
    {
      f32x4 z = {0.f, 0.f, 0.f, 0.f};
      gacc[0] = z; gacc[1] = z; gacc[2] = z; gacc[3] = z;
    }
    gstep(sh_xt, 0, wfrag[6]);  gstep(sh_xt, 32, wfrag[7]);
    gstep(sh_Y1, 0, wfrag[8]);  gstep(sh_Y1, 32, wfrag[9]);
    gstep(sh_Y2, 0, wfrag[10]); gstep(sh_Y2, 32, wfrag[11]);
    __syncthreads();

    // ---- Phase E: yh1 = At@h, yh2 = S2@h
#pragma unroll
    for (int i = 0; i < 3; ++i) {
      int id = w + 12 * i;
      if (id < 16)      tile64(sh_At, sh_hT, sh_Y1, id >> 2, id & 3);
      else if (id < 32) tile64(sh_S2, sh_hT, sh_Y2, (id - 16) >> 2, (id - 16) & 3);
    }
    __syncthreads();

    // ---- Phase F: gate += [h, yh1, yh2] @ W_h ; write preacts (+bias) to sh_G
    gstep(sh_h,  0, wfrag[0]); gstep(sh_h,  32, wfrag[1]);
    gstep(sh_Y1, 0, wfrag[2]); gstep(sh_Y1, 32, wfrag[3]);
    gstep(sh_Y2, 0, wfrag[4]); gstep(sh_Y2, 32, wfrag[5]);
    {
      float bias = sh_biasG[w * 16 + l15];
      u16* G = sh_G + gate * 4608;
      int col = (w & 3) * 16 + l15;
#pragma unroll
      for (int mt = 0; mt < 4; ++mt) {
#pragma unroll
        for (int r = 0; r < 4; ++r)
          G[(mt * 16 + quad * 4 + r) * ST + col] = f2bf(gacc[mt][r] + bias);
      }
    }
    if (tid < 64) sh_pooled[tid] = 0.f;
    __syncthreads();

    // ---- Phase G: h_new = sig(ff)*tanh(gg) + (1-sig)*tanh(cc); pooled partials
    {
      float psum = 0.f;
      int d = tid & 63;
#pragma unroll
      for (int i = 0; i < 6; ++i) {
        int idx = tid + i * 768;
        if (idx < 4096) {
          int n = idx >> 6;
          float ff = bf2f(sh_G[n * ST + d]);
          float gg = bf2f(sh_G[4608 + n * ST + d]);
          float cc = bf2f(sh_G[9216 + n * ST + d]);
          float sig = 1.f / (1.f + __expf(-ff));
          float tg = 1.f - 2.f / (__expf(2.f * gg) + 1.f);
          float tc = 1.f - 2.f / (__expf(2.f * cc) + 1.f);
          float hn = sig * tg + (1.f - sig) * tc;
          u16 hv = f2bf(hn);
          sh_h[n * ST + d]  = hv;
          sh_hT[d * ST + n] = hv;
          psum += hn;
          if (t == 127) stout(49152 + (b << 12) + idx, hn);  // final_hidden
        }
      }
      atomicAdd(&sh_pooled[d], psum);
    }
    __syncthreads();

    // ---- Phase H: wave0 decoder (this t) || waves 1..11 stage t+1
    if (w == 0) {
      int l = tid;  // 0..63
      float p = sh_pooled[l] * (1.f / 64.f);
      sh_pooled[l] = p;   // same-wave write->read ordering
      float a0 = ldf(db1, l), a1 = ldf(db1, l + 64);
      float c0 = 0.f, c1 = 0.f;
#pragma unroll 8
      for (int c = 0; c < 64; c += 2) {
        float p0 = sh_pooled[c], p1 = sh_pooled[c + 1];
        a0 += p0 * ldf(dW1, c * 128 + l);
        a1 += p0 * ldf(dW1, c * 128 + 64 + l);
        c0 += p1 * ldf(dW1, (c + 1) * 128 + l);
        c1 += p1 * ldf(dW1, (c + 1) * 128 + 64 + l);
      }
      sh_z1[l]      = fmaxf(a0 + c0, 0.f);
      sh_z1[l + 64] = fmaxf(a1 + c1, 0.f);
      float s0 = ldf(db2, l), s1 = 0.f, s2 = 0.f, s3 = 0.f;
#pragma unroll 8
      for (int c = 0; c < 128; c += 4) {
        s0 += sh_z1[c]     * ldf(dW2, c * 64 + l);
        s1 += sh_z1[c + 1] * ldf(dW2, (c + 1) * 64 + l);
        s2 += sh_z1[c + 2] * ldf(dW2, (c + 2) * 64 + l);
        s3 += sh_z1[c + 3] * ldf(dW2, (c + 3) * 64 + l);
      }
      sh_z2[l] = fmaxf(s0 + s1 + s2 + s3, 0.f);
      if (l < 6) {
        float acc = ldf(db3, l);
#pragma unroll 8
        for (int c = 0; c < 64; ++c) acc += sh_z2[c] * ldf(dW3, c * 6 + l);
        float val = acc * ldf(osc, l) + ldf(obi, l);
        stout((b * 128 + t) * 6 + l, val);   // controls
      }
    } else if (t < 127) {
      stage(t + 1, tid - 64, 704);
    }
    __syncthreads();
  }
}

extern "C" void kernel_launch(void* const* d_in, const int* in_sizes, int n_in,
                              void* d_out, int out_size, void* d_ws, size_t ws_size,
                              hipStream_t stream) {
  (void)in_sizes; (void)n_in; (void)out_size; (void)d_ws; (void)ws_size;
  cfgcn<<<dim3(64), dim3(768), 0, stream>>>(
      d_in[0], d_in[1], d_in[2], d_in[3], d_in[4], d_in[5], d_in[6], d_in[7],
      d_in[8], d_in[9], d_in[10], d_in[11], d_in[12], d_in[13], d_in[14], d_in[15],
      d_in[16], d_in[17], d_in[18], d_in[19], d_in[20], d_in[21], d_out);
}